// Round 1
// baseline (280.920 us; speedup 1.0000x reference)
//
#include <hip/hip_runtime.h>
#include <cstdint>
#include <cstddef>

#define D_     256
#define TWO_D  512
#define R_     16
#define N0_    8192
#define L_     6
#define NL_    8192
#define B_     512
#define TOTAL_ (N0_ + L_*NL_)

#define MT      32          // nodes (M) per block -> 256 blocks
#define XPITCH  520         // bf16 elems per X row (512 + 8 pad)
#define HPITCH  264         // bf16 elems per H row (256 + 8 pad)
#define OPITCH  264         // out-stage pitch (reuses X buffer)
#define NBLK    256         // == CU count; 1 block/CU => co-resident

using short8 = __attribute__((ext_vector_type(8))) short;   // 8 bf16 (4 VGPRs)
using f32x4  = __attribute__((ext_vector_type(4))) float;   // 4 fp32 acc

__device__ __forceinline__ unsigned short f2bf(float f) {
    union { float f; unsigned u; } v; v.f = f;
    unsigned u = v.u;
    return (unsigned short)((u + 0x7FFFu + ((u >> 16) & 1u)) >> 16);  // RNE
}
__device__ __forceinline__ float bf2f(unsigned short h) {
    union { unsigned u; float f; } v; v.u = ((unsigned)h) << 16;
    return v.f;
}
__device__ __forceinline__ float softplus_f(float x) {
    return fmaxf(x, 0.0f) + log1pf(expf(-fabsf(x)));
}

__device__ __forceinline__ void eval_accum(float x, float pos, float neg, float pw,
                                           float& loss, float& posTot, float& negTot,
                                           float& posOK, float& negOK) {
    float tot = pos + neg;
    if (tot > 0.0f) {
        float tgt = pos / fmaxf(tot, 1e-9f);
        loss += tot * (pw * tgt * softplus_f(-x) + (1.0f - tgt) * softplus_f(x));
        posTot += pos; negTot += neg;
        if (x >= 0.0f) posOK += pos; else negOK += neg;
    }
}

// Device-scope grid barrier. One fresh counter per phase (zeroed by wimg_k
// each launch, stream-ordered before fused_k). Release on arrive, acquire on
// spin; bounded spin as a no-hang safety valve (never triggers when all 256
// blocks are resident, which __launch_bounds__(512,2) + grid==256 guarantees).
__device__ __forceinline__ void grid_barrier(unsigned* bar, int phase) {
    __syncthreads();
    if (threadIdx.x == 0) {
        __threadfence();   // publish this block's global stores (agent scope)
        __hip_atomic_fetch_add(&bar[phase], 1u, __ATOMIC_RELEASE,
                               __HIP_MEMORY_SCOPE_AGENT);
        int guard = 0;
        while (__hip_atomic_load(&bar[phase], __ATOMIC_ACQUIRE,
                                 __HIP_MEMORY_SCOPE_AGENT) < (unsigned)NBLK) {
            __builtin_amdgcn_s_sleep(16);
            if (++guard > (1 << 20)) break;   // safety valve vs. deadlock
        }
    }
    __syncthreads();
}

// ---------------------------------------------------------------- prep ----
// W [r][K][256] fp32  ->  fragment image [r][ks][q][n][8] bf16.
// Also zeroes accum[0..7] and the 8 grid-barrier counters (accum[8..15]).
__global__ void wimg_k(const float* __restrict__ W,
                       unsigned short* __restrict__ img,
                       int KS, float* __restrict__ accum) {
    if (blockIdx.x == 0 && threadIdx.x < 16) accum[threadIdx.x] = 0.0f;
    int r  = blockIdx.x / KS;
    int ks = blockIdx.x - r * KS;
    const float* src = W + (size_t)r * KS * 32 * 256;
    #pragma unroll
    for (int it = 0; it < 4; ++it) {
        int item = it * 256 + threadIdx.x;      // 0..1023 = 4q x 256n
        int q = item >> 8, n = item & 255;
        short8 v;
        #pragma unroll
        for (int j = 0; j < 8; ++j)
            v[j] = (short)f2bf(src[(size_t)(ks * 32 + q * 8 + j) * 256 + n]);
        *(short8*)(img + ((((size_t)r * KS + ks) * 4 + q) * 256 + n) * 8) = v;
    }
}

// ---------------------------------------------------------------- fused ----
// One persistent kernel: init-gather+eval, 6 layers (grid barrier between),
// per-tile eval from the LDS out-stage, final reduce + finalize.
// Layer math is identical to the previous layer_k; GEMM2 additionally
// refills the B-register file with next layer's W1 ks=0..7 (weights are
// layer-invariant), so only the first layer pays the serial preload.
__global__ __launch_bounds__(512, 2)
void fused_k(unsigned short* __restrict__ storeb,
             const int* __restrict__ thax,
             const float* __restrict__ table,
             const int* __restrict__ par_all,           // [L][NL][2]
             const unsigned short* __restrict__ w1img,  // [R][16][4][256][8]
             const unsigned short* __restrict__ w2img,  // [R][8][4][256][8]
             const float* __restrict__ b1v,
             const float* __restrict__ b2v,
             const float* __restrict__ eval_w,
             const float* __restrict__ eval_b,
             const float* __restrict__ pos_vals,
             const float* __restrict__ neg_vals,
             const float* __restrict__ pos_weight,
             float* __restrict__ accum,
             unsigned* __restrict__ bar,
             float* __restrict__ out) {
    __shared__ unsigned short X[MT * XPITCH];   // 33280 B (also out-stage)
    __shared__ unsigned short H[MT * HPITCH];   // 16896 B
    __shared__ float shred[5];

    const int bid  = blockIdx.x;
    const int tid  = threadIdx.x;
    const int w    = tid >> 6;        // wave 0..7 -> n-slice base w*32
    const int lane = tid & 63;
    const int q    = lane >> 4;
    const int ml   = lane & 15;
    const int nb   = w * 32;

    const int r  = (bid & 7) | (((bid >> 3) & 1) << 3);   // XCD-local rule
    const int mt = bid >> 4;
    const int nodeInLayer0 = r * B_ + mt * MT;

    const float ew0 = eval_w[lane * 4 + 0], ew1 = eval_w[lane * 4 + 1];
    const float ew2 = eval_w[lane * 4 + 2], ew3 = eval_w[lane * 4 + 3];
    const float eb = eval_b[0], pw = pos_weight[0];
    float loss = 0.f, posTot = 0.f, negTot = 0.f, posOK = 0.f, negOK = 0.f;

    // ---- phase 0: init gather + eval. Block owns rows bid*32..+31;
    // wave w handles rows w*4+rr (one row per wave iteration, 1KB coalesced).
    {
        int base = bid * MT;
        #pragma unroll
        for (int rr = 0; rr < 4; ++rr) {
            int row = base + w * 4 + rr;
            int t = thax[row];
            float4 v = *(const float4*)(table + (size_t)t * D_ + lane * 4);
            ushort4 o;
            o.x = f2bf(v.x); o.y = f2bf(v.y); o.z = f2bf(v.z); o.w = f2bf(v.w);
            *(ushort4*)(storeb + (size_t)row * D_ + lane * 4) = o;
            // eval from the bf16-rounded values (bit-identical to old eval_k)
            float s = bf2f(o.x)*ew0 + bf2f(o.y)*ew1 + bf2f(o.z)*ew2 + bf2f(o.w)*ew3;
            #pragma unroll
            for (int off = 32; off > 0; off >>= 1) s += __shfl_down(s, off);
            if (lane == 0)
                eval_accum(s + eb, pos_vals[row], neg_vals[row], pw,
                           loss, posTot, negTot, posOK, negOK);
        }
    }
    grid_barrier(bar, 0);

    const unsigned short* w1r = w1img + (size_t)r * 16 * 4 * 256 * 8;
    const unsigned short* w2r = w2img + (size_t)r * 8 * 4 * 256 * 8;
    const size_t fb = (size_t)(q * 256 + nb + ml) * 8;   // per-lane frag base

    // --- B-fragment register file: preload W1 ks=0..7 (16 frags, 64 VGPR)
    short8 breg[16];
    #pragma unroll
    for (int p = 0; p < 8; ++p) {
        breg[p * 2 + 0] = *(const short8*)(&w1r[fb + (size_t)p * 8192]);
        breg[p * 2 + 1] = *(const short8*)(&w1r[fb + (size_t)p * 8192 + 128]);
    }

    for (int l = 0; l < L_; ++l) {
        const int* par = par_all + (size_t)l * NL_ * 2;

        // gather parents -> X: 32 rows x 2 parents x 32 chunks, 4/thread
        int pidx[4];
        #pragma unroll
        for (int it = 0; it < 4; ++it) {
            int c = it * 512 + tid;
            pidx[it] = par[(nodeInLayer0 + (c >> 6)) * 2 + ((c & 63) >> 5)];
        }
        #pragma unroll
        for (int it = 0; it < 4; ++it) {
            int c   = it * 512 + tid;
            int m   = c >> 6;
            int rem = c & 63;
            int j   = rem >> 5;
            int c16 = rem & 31;
            uint4 v = *((const uint4*)(storeb + (size_t)pidx[it] * D_) + c16);
            *((uint4*)(&X[m * XPITCH + j * D_ + c16 * 8])) = v;
        }
        __syncthreads();

        // ---- GEMM1: [32 x 512] @ [512 x 256] -> H, relu(.+b1) ----
        f32x4 acc[2][2] = {};
        #pragma unroll
        for (int ks = 0; ks < 16; ++ks) {
            int slot = (ks & 7) * 2;
            short8 bb0 = breg[slot + 0];
            short8 bb1 = breg[slot + 1];
            if (ks < 8) {
                breg[slot + 0] = *(const short8*)(&w1r[fb + (size_t)(ks + 8) * 8192]);
                breg[slot + 1] = *(const short8*)(&w1r[fb + (size_t)(ks + 8) * 8192 + 128]);
            } else {
                breg[slot + 0] = *(const short8*)(&w2r[fb + (size_t)(ks - 8) * 8192]);
                breg[slot + 1] = *(const short8*)(&w2r[fb + (size_t)(ks - 8) * 8192 + 128]);
            }
            int k0 = ks * 32 + q * 8;
            short8 a0 = *(const short8*)(&X[ml * XPITCH + k0]);
            short8 a1 = *(const short8*)(&X[(16 + ml) * XPITCH + k0]);
            acc[0][0] = __builtin_amdgcn_mfma_f32_16x16x32_bf16(a0, bb0, acc[0][0], 0, 0, 0);
            acc[1][0] = __builtin_amdgcn_mfma_f32_16x16x32_bf16(a1, bb0, acc[1][0], 0, 0, 0);
            acc[0][1] = __builtin_amdgcn_mfma_f32_16x16x32_bf16(a0, bb1, acc[0][1], 0, 0, 0);
            acc[1][1] = __builtin_amdgcn_mfma_f32_16x16x32_bf16(a1, bb1, acc[1][1], 0, 0, 0);
        }
        #pragma unroll
        for (int ni = 0; ni < 2; ++ni) {
            int n = nb + ni * 16 + ml;
            float bias = b1v[r * D_ + n];
            #pragma unroll
            for (int mi = 0; mi < 2; ++mi)
                #pragma unroll
                for (int v = 0; v < 4; ++v) {
                    int row = mi * 16 + q * 4 + v;   // C/D: row = quad*4+reg
                    float x = acc[mi][ni][v] + bias;
                    H[row * HPITCH + n] = f2bf(x > 0.0f ? x : 0.0f);
                }
        }
        __syncthreads();

        // ---- GEMM2: [32 x 256] @ [256 x 256] (+b2) — B in registers.
        // Refill slots with next layer's W1 ks=0..7 (weights layer-invariant).
        f32x4 acc2[2][2] = {};
        #pragma unroll
        for (int ks = 0; ks < 8; ++ks) {
            int slot = ks * 2;
            short8 bb0 = breg[slot + 0];
            short8 bb1 = breg[slot + 1];
            if (l != L_ - 1) {
                breg[slot + 0] = *(const short8*)(&w1r[fb + (size_t)ks * 8192]);
                breg[slot + 1] = *(const short8*)(&w1r[fb + (size_t)ks * 8192 + 128]);
            }
            int k0 = ks * 32 + q * 8;
            short8 a0 = *(const short8*)(&H[ml * HPITCH + k0]);
            short8 a1 = *(const short8*)(&H[(16 + ml) * HPITCH + k0]);
            acc2[0][0] = __builtin_amdgcn_mfma_f32_16x16x32_bf16(a0, bb0, acc2[0][0], 0, 0, 0);
            acc2[1][0] = __builtin_amdgcn_mfma_f32_16x16x32_bf16(a1, bb0, acc2[1][0], 0, 0, 0);
            acc2[0][1] = __builtin_amdgcn_mfma_f32_16x16x32_bf16(a0, bb1, acc2[0][1], 0, 0, 0);
            acc2[1][1] = __builtin_amdgcn_mfma_f32_16x16x32_bf16(a1, bb1, acc2[1][1], 0, 0, 0);
        }
        // X reads all finished before post-GEMM1 barrier -> reuse X as out-stage
        #pragma unroll
        for (int ni = 0; ni < 2; ++ni) {
            int n = nb + ni * 16 + ml;
            float bias = b2v[r * D_ + n];
            #pragma unroll
            for (int mi = 0; mi < 2; ++mi)
                #pragma unroll
                for (int v = 0; v < 4; ++v) {
                    int row = mi * 16 + q * 4 + v;
                    float x = acc2[mi][ni][v] + bias;
                    X[row * OPITCH + n] = f2bf(x);
                }
        }
        __syncthreads();

        size_t outBase = (size_t)(N0_ + l * NL_ + nodeInLayer0);
        // coalesced store (skip for the last layer: nobody gathers from it)
        if (l != L_ - 1) {
            #pragma unroll
            for (int it = 0; it < 2; ++it) {
                int c   = it * 512 + tid;       // 0..1023 = 32 rows x 32 chunks
                int m   = c >> 5;
                int c16 = c & 31;
                uint4 v = *((const uint4*)(&X[m * OPITCH]) + c16);
                *((uint4*)(storeb + (outBase + m) * D_) + c16) = v;
            }
        }
        // fused eval of this tile from the LDS out-stage (same bf16 values
        // the old eval_k re-read from HBM). Wave w -> rows w*4+rr.
        #pragma unroll
        for (int rr = 0; rr < 4; ++rr) {
            int row = w * 4 + rr;
            ushort4 vv = *(const ushort4*)(&X[row * OPITCH + lane * 4]);
            float s = bf2f(vv.x)*ew0 + bf2f(vv.y)*ew1 + bf2f(vv.z)*ew2 + bf2f(vv.w)*ew3;
            #pragma unroll
            for (int off = 32; off > 0; off >>= 1) s += __shfl_down(s, off);
            if (lane == 0)
                eval_accum(s + eb, pos_vals[outBase + row], neg_vals[outBase + row], pw,
                           loss, posTot, negTot, posOK, negOK);
        }
        if (l != L_ - 1) grid_barrier(bar, 1 + l);   // phases 1..5
    }

    // ---- final reduce: block-local via LDS, one atomicAdd set per block
    if (tid < 5) shred[tid] = 0.0f;
    __syncthreads();
    if (lane == 0) {
        atomicAdd(&shred[0], loss);
        atomicAdd(&shred[1], posTot);
        atomicAdd(&shred[2], negTot);
        atomicAdd(&shred[3], posOK);
        atomicAdd(&shred[4], negOK);
    }
    __syncthreads();
    if (tid < 5) atomicAdd(&accum[tid], shred[tid]);
    grid_barrier(bar, 6);
    if (bid == 0 && tid == 0) {
        float vloss   = __hip_atomic_load(&accum[0], __ATOMIC_RELAXED, __HIP_MEMORY_SCOPE_AGENT);
        float vposTot = __hip_atomic_load(&accum[1], __ATOMIC_RELAXED, __HIP_MEMORY_SCOPE_AGENT);
        float vnegTot = __hip_atomic_load(&accum[2], __ATOMIC_RELAXED, __HIP_MEMORY_SCOPE_AGENT);
        float vposOK  = __hip_atomic_load(&accum[3], __ATOMIC_RELAXED, __HIP_MEMORY_SCOPE_AGENT);
        float vnegOK  = __hip_atomic_load(&accum[4], __ATOMIC_RELAXED, __HIP_MEMORY_SCOPE_AGENT);
        out[0] = vloss;
        out[1] = (vposTot > 0.0f) ? vposOK / fmaxf(vposTot, 1e-9f) : 1.0f;
        out[2] = (vnegTot > 0.0f) ? vnegOK / fmaxf(vnegTot, 1e-9f) : 1.0f;
    }
}

// ---------------------------------------------------------------- launch ---
extern "C" void kernel_launch(void* const* d_in, const int* in_sizes, int n_in,
                              void* d_out, int out_size, void* d_ws, size_t ws_size,
                              hipStream_t stream) {
    const int*   thax       = (const int*)  d_in[0];
    const int*   par        = (const int*)  d_in[1];
    const float* pos_vals   = (const float*)d_in[2];
    const float* neg_vals   = (const float*)d_in[3];
    const float* init_table = (const float*)d_in[4];
    const float* W1         = (const float*)d_in[5];
    const float* b1         = (const float*)d_in[6];
    const float* W2         = (const float*)d_in[7];
    const float* b2         = (const float*)d_in[8];
    const float* eval_w     = (const float*)d_in[9];
    const float* eval_b     = (const float*)d_in[10];
    const float* pos_weight = (const float*)d_in[11];
    float* out = (float*)d_out;

    char* ws = (char*)d_ws;
    unsigned short* w1img  = (unsigned short*)(ws);                            // 4 MB
    unsigned short* w2img  = (unsigned short*)(ws + (size_t)4  * 1024 * 1024); // 2 MB
    unsigned short* storeb = (unsigned short*)(ws + (size_t)6  * 1024 * 1024); // 28 MB
    float*          accum  = (float*)(ws + (size_t)6 * 1024 * 1024 +
                                      (size_t)TOTAL_ * D_ * 2);
    unsigned*       bar    = (unsigned*)(accum + 8);   // 8 barrier counters

    hipLaunchKernelGGL(wimg_k, dim3(R_ * 16), dim3(256), 0, stream,
                       W1, w1img, 16, accum);
    hipLaunchKernelGGL(wimg_k, dim3(R_ * 8), dim3(256), 0, stream,
                       W2, w2img, 8, accum);
    hipLaunchKernelGGL(fused_k, dim3(NBLK), dim3(512), 0, stream,
                       storeb, thax, init_table, par, w1img, w2img, b1, b2,
                       eval_w, eval_b, pos_vals, neg_vals, pos_weight,
                       accum, bar, out);
}

// Round 2
// 199.087 us; speedup vs baseline: 1.4110x; 1.4110x over previous
//
#include <hip/hip_runtime.h>
#include <cstdint>
#include <cstddef>

#define D_     256
#define TWO_D  512
#define R_     16
#define N0_    8192
#define L_     6
#define NL_    8192
#define B_     512
#define TOTAL_ (N0_ + L_*NL_)

#define MT      32          // nodes (M) per block -> 256 blocks
#define XPITCH  520         // bf16 elems per X row (512 + 8 pad)
#define HPITCH  264         // bf16 elems per H row (256 + 8 pad)
#define OPITCH  264         // out-stage pitch (reuses X buffer)
#define NBLK    256         // == CU count; 1 block/CU => co-resident

using short8 = __attribute__((ext_vector_type(8))) short;   // 8 bf16 (4 VGPRs)
using f32x4  = __attribute__((ext_vector_type(4))) float;   // 4 fp32 acc

__device__ __forceinline__ unsigned short f2bf(float f) {
    union { float f; unsigned u; } v; v.f = f;
    unsigned u = v.u;
    return (unsigned short)((u + 0x7FFFu + ((u >> 16) & 1u)) >> 16);  // RNE
}
__device__ __forceinline__ float bf2f(unsigned short h) {
    union { unsigned u; float f; } v; v.u = ((unsigned)h) << 16;
    return v.f;
}
__device__ __forceinline__ float softplus_f(float x) {
    return fmaxf(x, 0.0f) + log1pf(expf(-fabsf(x)));
}

__device__ __forceinline__ void eval_accum(float x, float pos, float neg, float pw,
                                           float& loss, float& posTot, float& negTot,
                                           float& posOK, float& negOK) {
    float tot = pos + neg;
    if (tot > 0.0f) {
        float tgt = pos / fmaxf(tot, 1e-9f);
        loss += tot * (pw * tgt * softplus_f(-x) + (1.0f - tgt) * softplus_f(x));
        posTot += pos; negTot += neg;
        if (x >= 0.0f) posOK += pos; else negOK += neg;
    }
}

// Device-scope grid barrier, v2: RELAXED spin (no cache ops per poll!) with
// exactly ONE release fence before arrive and ONE acquire fence after exit.
// v1's ACQUIRE-per-poll emitted buffer_inv every iteration, continuously
// invalidating the XCD's L1/L2 under co-resident blocks — the measured
// disaster (218 us, 56 MB FETCH from per-layer weight re-fetch).
__device__ __forceinline__ void grid_barrier(unsigned* bar, int phase) {
    __syncthreads();
    if (threadIdx.x == 0) {
        __builtin_amdgcn_fence(__ATOMIC_RELEASE, "agent");   // publish stores (1x wbL2)
        __hip_atomic_fetch_add(&bar[phase], 1u, __ATOMIC_RELAXED,
                               __HIP_MEMORY_SCOPE_AGENT);
        unsigned guard = 0;
        while (__hip_atomic_load(&bar[phase], __ATOMIC_RELAXED,
                                 __HIP_MEMORY_SCOPE_AGENT) < (unsigned)NBLK) {
            __builtin_amdgcn_s_sleep(4);
            if (++guard > (1u << 22)) break;   // safety valve vs. deadlock
        }
        __builtin_amdgcn_fence(__ATOMIC_ACQUIRE, "agent");   // 1x inv on exit
    }
    __syncthreads();
}

// ---------------------------------------------------------------- prep ----
// W [r][K][256] fp32 -> fragment image [r][ks][q][n][8] bf16. One kernel for
// both W1 (blocks 0..255) and W2 (blocks 256..383). Also zeroes accum[0..7]
// and the 8 grid-barrier counters (accum[8..15]).
__global__ void wimg_k(const float* __restrict__ W1in,
                       const float* __restrict__ W2in,
                       unsigned short* __restrict__ img1,
                       unsigned short* __restrict__ img2,
                       float* __restrict__ accum) {
    if (blockIdx.x == 0 && threadIdx.x < 16) accum[threadIdx.x] = 0.0f;
    int b = blockIdx.x;
    const float* W; unsigned short* img; int KS, rb;
    if (b < R_ * 16) { W = W1in; img = img1; KS = 16; rb = b; }
    else             { W = W2in; img = img2; KS = 8;  rb = b - R_ * 16; }
    int r  = rb / KS;
    int ks = rb - r * KS;
    const float* src = W + (size_t)r * KS * 32 * 256;
    #pragma unroll
    for (int it = 0; it < 4; ++it) {
        int item = it * 256 + threadIdx.x;      // 0..1023 = 4q x 256n
        int q = item >> 8, n = item & 255;
        short8 v;
        #pragma unroll
        for (int j = 0; j < 8; ++j)
            v[j] = (short)f2bf(src[(size_t)(ks * 32 + q * 8 + j) * 256 + n]);
        *(short8*)(img + ((((size_t)r * KS + ks) * 4 + q) * 256 + n) * 8) = v;
    }
}

// ---------------------------------------------------------------- fused ----
// One persistent kernel. v2 changes vs v1:
//  * ALL 48 B-fragment pairs (W1 16ks + W2 8ks, 192 VGPRs) are loaded ONCE
//    in the prologue and stay register-resident for all 6 layers — zero
//    weight memory traffic inside the layer loop. (We run 1 block/CU, so the
//    VGPR budget is 256; streaming was only ever needed for occupancy we
//    don't use.)  All breg indices are compile-time constants (rule #20).
//  * grid_barrier v2 (relaxed spin, single acquire/release fence).
__global__ __launch_bounds__(512, 2)
void fused_k(unsigned short* __restrict__ storeb,
             const int* __restrict__ thax,
             const float* __restrict__ table,
             const int* __restrict__ par_all,           // [L][NL][2]
             const unsigned short* __restrict__ w1img,  // [R][16][4][256][8]
             const unsigned short* __restrict__ w2img,  // [R][8][4][256][8]
             const float* __restrict__ b1v,
             const float* __restrict__ b2v,
             const float* __restrict__ eval_w,
             const float* __restrict__ eval_b,
             const float* __restrict__ pos_vals,
             const float* __restrict__ neg_vals,
             const float* __restrict__ pos_weight,
             float* __restrict__ accum,
             unsigned* __restrict__ bar,
             float* __restrict__ out) {
    __shared__ unsigned short X[MT * XPITCH];   // 33280 B (also out-stage)
    __shared__ unsigned short H[MT * HPITCH];   // 16896 B
    __shared__ float shred[5];

    const int bid  = blockIdx.x;
    const int tid  = threadIdx.x;
    const int w    = tid >> 6;        // wave 0..7 -> n-slice base w*32
    const int lane = tid & 63;
    const int q    = lane >> 4;
    const int ml   = lane & 15;
    const int nb   = w * 32;

    const int r  = (bid & 7) | (((bid >> 3) & 1) << 3);   // XCD-local rule
    const int mt = bid >> 4;
    const int nodeInLayer0 = r * B_ + mt * MT;

    // --- full W register file: W1 ks=0..15 -> slots 0..31, W2 ks=0..7 ->
    // slots 32..47. Loaded once; L3-latency overlaps the init phase below.
    const unsigned short* w1r = w1img + (size_t)r * 16 * 4 * 256 * 8;
    const unsigned short* w2r = w2img + (size_t)r * 8 * 4 * 256 * 8;
    const size_t fb = (size_t)(q * 256 + nb + ml) * 8;   // per-lane frag base
    short8 breg[48];
    #pragma unroll
    for (int p = 0; p < 16; ++p) {
        breg[p * 2 + 0] = *(const short8*)(&w1r[fb + (size_t)p * 8192]);
        breg[p * 2 + 1] = *(const short8*)(&w1r[fb + (size_t)p * 8192 + 128]);
    }
    #pragma unroll
    for (int p = 0; p < 8; ++p) {
        breg[32 + p * 2 + 0] = *(const short8*)(&w2r[fb + (size_t)p * 8192]);
        breg[32 + p * 2 + 1] = *(const short8*)(&w2r[fb + (size_t)p * 8192 + 128]);
    }

    const float ew0 = eval_w[lane * 4 + 0], ew1 = eval_w[lane * 4 + 1];
    const float ew2 = eval_w[lane * 4 + 2], ew3 = eval_w[lane * 4 + 3];
    const float eb = eval_b[0], pw = pos_weight[0];
    float loss = 0.f, posTot = 0.f, negTot = 0.f, posOK = 0.f, negOK = 0.f;

    // ---- phase 0: init gather + eval (overlaps the weight preload above).
    {
        int base = bid * MT;
        #pragma unroll
        for (int rr = 0; rr < 4; ++rr) {
            int row = base + w * 4 + rr;
            int t = thax[row];
            float4 v = *(const float4*)(table + (size_t)t * D_ + lane * 4);
            ushort4 o;
            o.x = f2bf(v.x); o.y = f2bf(v.y); o.z = f2bf(v.z); o.w = f2bf(v.w);
            *(ushort4*)(storeb + (size_t)row * D_ + lane * 4) = o;
            float s = bf2f(o.x)*ew0 + bf2f(o.y)*ew1 + bf2f(o.z)*ew2 + bf2f(o.w)*ew3;
            #pragma unroll
            for (int off = 32; off > 0; off >>= 1) s += __shfl_down(s, off);
            if (lane == 0)
                eval_accum(s + eb, pos_vals[row], neg_vals[row], pw,
                           loss, posTot, negTot, posOK, negOK);
        }
    }
    grid_barrier(bar, 0);

    for (int l = 0; l < L_; ++l) {
        const int* par = par_all + (size_t)l * NL_ * 2;

        // gather parents -> X: 32 rows x 2 parents x 32 chunks, 4/thread
        int pidx[4];
        #pragma unroll
        for (int it = 0; it < 4; ++it) {
            int c = it * 512 + tid;
            pidx[it] = par[(nodeInLayer0 + (c >> 6)) * 2 + ((c & 63) >> 5)];
        }
        #pragma unroll
        for (int it = 0; it < 4; ++it) {
            int c   = it * 512 + tid;
            int m   = c >> 6;
            int rem = c & 63;
            int j   = rem >> 5;
            int c16 = rem & 31;
            uint4 v = *((const uint4*)(storeb + (size_t)pidx[it] * D_) + c16);
            *((uint4*)(&X[m * XPITCH + j * D_ + c16 * 8])) = v;
        }
        __syncthreads();

        // ---- GEMM1: [32 x 512] @ [512 x 256] -> H, relu(.+b1). B in regs.
        f32x4 acc[2][2] = {};
        #pragma unroll
        for (int ks = 0; ks < 16; ++ks) {
            int k0 = ks * 32 + q * 8;
            short8 a0 = *(const short8*)(&X[ml * XPITCH + k0]);
            short8 a1 = *(const short8*)(&X[(16 + ml) * XPITCH + k0]);
            acc[0][0] = __builtin_amdgcn_mfma_f32_16x16x32_bf16(a0, breg[ks*2+0], acc[0][0], 0, 0, 0);
            acc[1][0] = __builtin_amdgcn_mfma_f32_16x16x32_bf16(a1, breg[ks*2+0], acc[1][0], 0, 0, 0);
            acc[0][1] = __builtin_amdgcn_mfma_f32_16x16x32_bf16(a0, breg[ks*2+1], acc[0][1], 0, 0, 0);
            acc[1][1] = __builtin_amdgcn_mfma_f32_16x16x32_bf16(a1, breg[ks*2+1], acc[1][1], 0, 0, 0);
        }
        #pragma unroll
        for (int ni = 0; ni < 2; ++ni) {
            int n = nb + ni * 16 + ml;
            float bias = b1v[r * D_ + n];
            #pragma unroll
            for (int mi = 0; mi < 2; ++mi)
                #pragma unroll
                for (int v = 0; v < 4; ++v) {
                    int row = mi * 16 + q * 4 + v;   // C/D: row = quad*4+reg
                    float x = acc[mi][ni][v] + bias;
                    H[row * HPITCH + n] = f2bf(x > 0.0f ? x : 0.0f);
                }
        }
        __syncthreads();

        // ---- GEMM2: [32 x 256] @ [256 x 256] (+b2). B in regs (slots 32+).
        f32x4 acc2[2][2] = {};
        #pragma unroll
        for (int ks = 0; ks < 8; ++ks) {
            int k0 = ks * 32 + q * 8;
            short8 a0 = *(const short8*)(&H[ml * HPITCH + k0]);
            short8 a1 = *(const short8*)(&H[(16 + ml) * HPITCH + k0]);
            acc2[0][0] = __builtin_amdgcn_mfma_f32_16x16x32_bf16(a0, breg[32+ks*2+0], acc2[0][0], 0, 0, 0);
            acc2[1][0] = __builtin_amdgcn_mfma_f32_16x16x32_bf16(a1, breg[32+ks*2+0], acc2[1][0], 0, 0, 0);
            acc2[0][1] = __builtin_amdgcn_mfma_f32_16x16x32_bf16(a0, breg[32+ks*2+1], acc2[0][1], 0, 0, 0);
            acc2[1][1] = __builtin_amdgcn_mfma_f32_16x16x32_bf16(a1, breg[32+ks*2+1], acc2[1][1], 0, 0, 0);
        }
        // X reads all finished before post-GEMM1 barrier -> reuse X as out-stage
        #pragma unroll
        for (int ni = 0; ni < 2; ++ni) {
            int n = nb + ni * 16 + ml;
            float bias = b2v[r * D_ + n];
            #pragma unroll
            for (int mi = 0; mi < 2; ++mi)
                #pragma unroll
                for (int v = 0; v < 4; ++v) {
                    int row = mi * 16 + q * 4 + v;
                    float x = acc2[mi][ni][v] + bias;
                    X[row * OPITCH + n] = f2bf(x);
                }
        }
        __syncthreads();

        size_t outBase = (size_t)(N0_ + l * NL_ + nodeInLayer0);
        // coalesced store (skip for the last layer: nobody gathers from it)
        if (l != L_ - 1) {
            #pragma unroll
            for (int it = 0; it < 2; ++it) {
                int c   = it * 512 + tid;       // 0..1023 = 32 rows x 32 chunks
                int m   = c >> 5;
                int c16 = c & 31;
                uint4 v = *((const uint4*)(&X[m * OPITCH]) + c16);
                *((uint4*)(storeb + (outBase + m) * D_) + c16) = v;
            }
        }
        // fused eval of this tile from the LDS out-stage
        #pragma unroll
        for (int rr = 0; rr < 4; ++rr) {
            int row = w * 4 + rr;
            ushort4 vv = *(const ushort4*)(&X[row * OPITCH + lane * 4]);
            float s = bf2f(vv.x)*ew0 + bf2f(vv.y)*ew1 + bf2f(vv.z)*ew2 + bf2f(vv.w)*ew3;
            #pragma unroll
            for (int off = 32; off > 0; off >>= 1) s += __shfl_down(s, off);
            if (lane == 0)
                eval_accum(s + eb, pos_vals[outBase + row], neg_vals[outBase + row], pw,
                           loss, posTot, negTot, posOK, negOK);
        }
        if (l != L_ - 1) grid_barrier(bar, 1 + l);   // phases 1..5
    }

    // ---- final reduce: block-local via LDS, one device-atomic set per block
    if (tid < 5) shred[tid] = 0.0f;
    __syncthreads();
    if (lane == 0) {
        atomicAdd(&shred[0], loss);
        atomicAdd(&shred[1], posTot);
        atomicAdd(&shred[2], negTot);
        atomicAdd(&shred[3], posOK);
        atomicAdd(&shred[4], negOK);
    }
    __syncthreads();
    if (tid < 5) atomicAdd(&accum[tid], shred[tid]);
    __syncthreads();
    // last barrier: blocks != 0 arrive and EXIT (no spin); block 0 waits,
    // then finalizes. accum adds are device-scope atomics (coherence point),
    // so arrival order via bar[6] is sufficient.
    if (tid == 0) {
        __builtin_amdgcn_fence(__ATOMIC_RELEASE, "agent");
        __hip_atomic_fetch_add(&bar[6], 1u, __ATOMIC_RELAXED,
                               __HIP_MEMORY_SCOPE_AGENT);
        if (bid == 0) {
            unsigned guard = 0;
            while (__hip_atomic_load(&bar[6], __ATOMIC_RELAXED,
                                     __HIP_MEMORY_SCOPE_AGENT) < (unsigned)NBLK) {
                __builtin_amdgcn_s_sleep(4);
                if (++guard > (1u << 22)) break;
            }
            __builtin_amdgcn_fence(__ATOMIC_ACQUIRE, "agent");
            float vloss   = __hip_atomic_load(&accum[0], __ATOMIC_RELAXED, __HIP_MEMORY_SCOPE_AGENT);
            float vposTot = __hip_atomic_load(&accum[1], __ATOMIC_RELAXED, __HIP_MEMORY_SCOPE_AGENT);
            float vnegTot = __hip_atomic_load(&accum[2], __ATOMIC_RELAXED, __HIP_MEMORY_SCOPE_AGENT);
            float vposOK  = __hip_atomic_load(&accum[3], __ATOMIC_RELAXED, __HIP_MEMORY_SCOPE_AGENT);
            float vnegOK  = __hip_atomic_load(&accum[4], __ATOMIC_RELAXED, __HIP_MEMORY_SCOPE_AGENT);
            out[0] = vloss;
            out[1] = (vposTot > 0.0f) ? vposOK / fmaxf(vposTot, 1e-9f) : 1.0f;
            out[2] = (vnegTot > 0.0f) ? vnegOK / fmaxf(vnegTot, 1e-9f) : 1.0f;
        }
    }
}

// ---------------------------------------------------------------- launch ---
extern "C" void kernel_launch(void* const* d_in, const int* in_sizes, int n_in,
                              void* d_out, int out_size, void* d_ws, size_t ws_size,
                              hipStream_t stream) {
    const int*   thax       = (const int*)  d_in[0];
    const int*   par        = (const int*)  d_in[1];
    const float* pos_vals   = (const float*)d_in[2];
    const float* neg_vals   = (const float*)d_in[3];
    const float* init_table = (const float*)d_in[4];
    const float* W1         = (const float*)d_in[5];
    const float* b1         = (const float*)d_in[6];
    const float* W2         = (const float*)d_in[7];
    const float* b2         = (const float*)d_in[8];
    const float* eval_w     = (const float*)d_in[9];
    const float* eval_b     = (const float*)d_in[10];
    const float* pos_weight = (const float*)d_in[11];
    float* out = (float*)d_out;

    char* ws = (char*)d_ws;
    unsigned short* w1img  = (unsigned short*)(ws);                            // 4 MB
    unsigned short* w2img  = (unsigned short*)(ws + (size_t)4  * 1024 * 1024); // 2 MB
    unsigned short* storeb = (unsigned short*)(ws + (size_t)6  * 1024 * 1024); // 28 MB
    float*          accum  = (float*)(ws + (size_t)6 * 1024 * 1024 +
                                      (size_t)TOTAL_ * D_ * 2);
    unsigned*       bar    = (unsigned*)(accum + 8);   // 8 barrier counters

    hipLaunchKernelGGL(wimg_k, dim3(R_ * 16 + R_ * 8), dim3(256), 0, stream,
                       W1, W2, w1img, w2img, accum);
    hipLaunchKernelGGL(fused_k, dim3(NBLK), dim3(512), 0, stream,
                       storeb, thax, init_table, par, w1img, w2img, b1, b2,
                       eval_w, eval_b, pos_vals, neg_vals, pos_weight,
                       accum, bar, out);
}